// Round 1
// 298.930 us; speedup vs baseline: 1.0315x; 1.0315x over previous
//
#include <hip/hip_runtime.h>
#include <stdint.h>

#define KPS 512
#define NBOX 1536
#define NBINS 1024

// scale cell counts: 32*H*H*3
#define S13 16224
#define S26 64896
#define S52 259584
#define TOTCELL 340704

__device__ __forceinline__ uint32_t f2u(float x){ union{float f;uint32_t u;}v; v.f=x; return v.u; }
__device__ __forceinline__ float u2f(uint32_t x){ union{float f;uint32_t u;}v; v.u=x; return v.f; }

__device__ __forceinline__ int binOf(float s){
    int b = (int)((s - 0.6f) * 2560.0f);    // 1024 bins over (0.6, 1.0)
    if (b < 0) b = 0;
    if (b > NBINS-1) b = NBINS-1;
    return b;
}

// counters: [3..5] abovePos, [6..8] stashCnt, [9..11] cutoffB, [12..14] aboveCount
__global__ void k_init(int* hist, int* cnt){
    int id = blockIdx.x*256 + threadIdx.x;
    if (id < 3*NBINS) hist[id] = 0;
    if (id < 32) cnt[id] = 0;
}

// Sparse candidate slots: cand[id] = key or 0. No wave-stalling atomics.
__global__ void k_score(const float* __restrict__ o13, const float* __restrict__ o26,
                        const float* __restrict__ o52,
                        unsigned long long* __restrict__ cand, int* __restrict__ hist){
    int id = blockIdx.x*256 + threadIdx.x;
    if (id >= TOTCELL) return;
    int scale, idl, H;
    const float* src;
    if (id < S13)            { scale=0; idl=id;            H=13; src=o13; }
    else if (id < S13+S26)   { scale=1; idl=id-S13;        H=26; src=o26; }
    else                     { scale=2; idl=id-(S13+S26);  H=52; src=o52; }
    int HW = H*H;
    // plane-major thread mapping for coalescing: idl = p*HW + hw, p = n*3 + a
    int p  = idl / HW;
    int hw = idl - p*HW;
    int n  = p / 3;
    int a  = p - n*3;
    int cidx = (n*HW + hw)*3 + a;       // reference flat cell index
    float x = src[(size_t)(n*255 + a*85)*HW + hw];
    float s = (float)(1.0 / (1.0 + exp(-(double)x)));   // correctly-rounded f32 sigmoid
    unsigned long long key = 0ull;
    if (s > 0.6f){
        key = ((unsigned long long)f2u(s) << 20)
            | ((unsigned long long)(2-scale) << 18)
            | (unsigned long long)(262143 - cidx);
        atomicAdd(&hist[scale*NBINS + binOf(s)], 1);   // fire-and-forget, spread bins
    }
    cand[id] = key;
}

__global__ void __launch_bounds__(1024) k_cutoff(const int* __restrict__ hist, int* __restrict__ cnt){
    int s = blockIdx.x, t = threadIdx.x;
    __shared__ int suf[NBINS];
    int h = hist[s*NBINS + t];
    suf[t] = h; __syncthreads();
    for (int d=1; d<NBINS; d<<=1){
        int v = (t+d < NBINS) ? suf[t+d] : 0;
        __syncthreads();
        suf[t] += v;
        __syncthreads();
    }
    int total = suf[0];
    int A = (t < NBINS-1) ? suf[t+1] : 0;   // count strictly above bin t
    if (t == 0 && total < KPS){ cnt[9+s] = -1; cnt[12+s] = total; }
    if (A < KPS && A + h >= KPS){ cnt[9+s] = t; cnt[12+s] = A; }
}

__global__ void k_classify(const unsigned long long* __restrict__ cand, int* __restrict__ cnt,
                           unsigned long long* __restrict__ sel, unsigned long long* __restrict__ stash){
    int id = blockIdx.x*256 + threadIdx.x;
    unsigned long long key = (id < TOTCELL) ? cand[id] : 0ull;
    bool live = (key != 0ull);
    int scale = live ? (2 - (int)((key >> 18) & 3ull)) : 0;
    int bin = live ? binOf(u2f((uint32_t)(key >> 20))) : -2;
    int B = cnt[9+scale];
    int lane = threadIdx.x & 63;
    unsigned long long lanebit_m1 = (lane == 63) ? ~0ull >> 1 : ((1ull << lane) - 1ull);
    bool above = live && (bin > B);
    bool bound = live && (bin == B);
    // wave-aggregate both counters (waves may straddle scales; loop scales)
    #pragma unroll
    for (int sc = 0; sc < 3; sc++){
        unsigned long long ma = __ballot(above && scale == sc);
        if (ma){
            int leader = __ffsll((long long)ma) - 1;
            int base = 0;
            if (lane == leader) base = atomicAdd(&cnt[3+sc], __popcll(ma));
            base = __shfl(base, leader);
            if (above && scale == sc)
                sel[sc*KPS + base + __popcll(ma & lanebit_m1)] = key;
        }
        unsigned long long mb = __ballot(bound && scale == sc);
        if (mb){
            int leader = __ffsll((long long)mb) - 1;
            int base = 0;
            if (lane == leader) base = atomicAdd(&cnt[6+sc], __popcll(mb));
            base = __shfl(base, leader);
            if (bound && scale == sc){
                int q = base + __popcll(mb & lanebit_m1);
                if (q < 1024) stash[sc*1024 + q] = key;
            }
        }
    }
}

__global__ void __launch_bounds__(1024) k_finalize(const int* __restrict__ cnt,
                           unsigned long long* __restrict__ sel, const unsigned long long* __restrict__ stash){
    int s = blockIdx.x, t = threadIdx.x;
    __shared__ unsigned long long sk[1024];
    int sc = cnt[6+s]; if (sc > 1024) sc = 1024;
    sk[t] = (t < sc) ? stash[s*1024 + t] : 0ull;
    __syncthreads();
    for (int k=2; k<=1024; k<<=1)
        for (int j=k>>1; j>0; j>>=1){
            int ixj = t ^ j;
            if (ixj > t){
                bool up = ((t & k) == 0);   // descending overall
                unsigned long long a = sk[t], b = sk[ixj];
                if (up ? (a < b) : (a > b)){ sk[t] = b; sk[ixj] = a; }
            }
            __syncthreads();
        }
    int above = cnt[12+s];
    int need = KPS - above; if (need < 0) need = 0;
    int m = (need < sc) ? need : sc;
    if (t < m) sel[s*KPS + above + t] = sk[t];
    if (t >= above + m && t < KPS) sel[s*KPS + t] = 0ull;   // sentinels
}

__global__ void k_decode(const float* __restrict__ o13, const float* __restrict__ o26,
                         const float* __restrict__ o52,
                         const float* __restrict__ a13, const float* __restrict__ a26,
                         const float* __restrict__ a52,
                         const unsigned long long* __restrict__ sel, float* __restrict__ boxes){
    int gtid = blockIdx.x*256 + threadIdx.x;
    int b = gtid >> 6;
    int lane = threadIdx.x & 63;
    if (b >= NBOX) return;
    unsigned long long key = sel[b];
    float* row = boxes + b*12;
    if ((key >> 20) == 0ull){           // sentinel
        if (lane < 9) row[lane] = 0.f;
        return;
    }
    int scale = 2 - (int)((key >> 18) & 3ull);
    int cidx  = 262143 - (int)(key & 0x3FFFFull);
    uint32_t sbits = (uint32_t)(key >> 20);
    const float* src; const float* anch; int H; float tt;
    if (scale == 0){ src=o13; anch=a13; H=13; tt=32.f; }
    else if (scale == 1){ src=o26; anch=a26; H=26; tt=16.f; }
    else { src=o52; anch=a52; H=52; tt=8.f; }
    int HW = H*H;
    int a  = cidx % 3;
    int hw = (cidx/3) % HW;
    int n  = cidx / (3*HW);
    int hh = hw / H;
    int ww = hw - hh*H;
    const float* cellbase = src + (size_t)(n*255 + a*85)*HW + hw;
    // argmax over 80 classes, tie -> lowest class index
    float bv = cellbase[(size_t)(5 + lane)*HW];
    int bi = lane;
    if (lane < 16){
        float v2 = cellbase[(size_t)(69 + lane)*HW];
        if (v2 > bv){ bv = v2; bi = 64 + lane; }
    }
    #pragma unroll
    for (int off=32; off; off>>=1){
        float vo = __shfl_xor(bv, off);
        int io = __shfl_xor(bi, off);
        if (vo > bv || (vo == bv && io < bi)){ bv = vo; bi = io; }
    }
    if (lane == 0){
        float v1 = cellbase[(size_t)1*HW];
        float v2 = cellbase[(size_t)2*HW];
        float v3 = cellbase[(size_t)3*HW];
        float v4 = cellbase[(size_t)4*HW];
        float cx = ((float)ww + v1) * tt / 416.0f;
        float cy = ((float)hh + v2) * tt / 416.0f;
        float e3 = (float)exp((double)v3);
        float e4 = (float)exp((double)v4);
        float bw = anch[a*2+0] * e3 / 416.0f;
        float bh = anch[a*2+1] * e4 / 416.0f;
        row[0] = (float)n;  row[1] = cx; row[2] = cy; row[3] = bw; row[4] = bh;
        row[5] = u2f(sbits); row[6] = (float)bi; row[7] = (float)hh; row[8] = (float)ww;
    }
}

__global__ void __launch_bounds__(1024) k_sort(const unsigned long long* __restrict__ sel,
                       const float* __restrict__ boxes, float* __restrict__ sboxes,
                       unsigned long long* __restrict__ vwords){
    __shared__ unsigned long long sk[2048];
    int t = threadIdx.x;
    for (int r=t; r<2048; r+=1024)
        sk[r] = (r < NBOX) ? ((sel[r] << 12) | (unsigned long long)r) : 0ull;
    __syncthreads();
    for (int k=2; k<=2048; k<<=1)
        for (int j=k>>1; j>0; j>>=1){
            for (int i=t; i<2048; i+=1024){
                int ixj = i ^ j;
                if (ixj > i){
                    bool up = ((i & k) == 0);
                    unsigned long long a = sk[i], b = sk[ixj];
                    if (up ? (a < b) : (a > b)){ sk[i] = b; sk[ixj] = a; }
                }
            }
            __syncthreads();
        }
    for (int r=t; r<2048; r+=1024){
        if (r < NBOX){
            unsigned long long key = sk[r];
            bool valid = (key >> 32) != 0ull;     // top 32 bits = sigmoid bits
            int slot = (int)(key & 0xFFFull);
            #pragma unroll
            for (int c=0;c<9;c++) sboxes[r*12+c] = valid ? boxes[slot*12+c] : 0.f;
            unsigned long long ball = __ballot(valid);
            if ((r & 63) == 0) vwords[r >> 6] = ball;
        }
    }
}

// Column-sliced suppression matrix: Tcol[i*64 + j] bit c = sup(i, c*64+j).
// Diagonal-tile ROW masks: diagR[i] bit j = sup(i, gi*64+j) where gi = i>>6.
// (row format -> the NMS resolve chain is pure scalar: ffs + readlane, no ballots)
__global__ void k_masks(const float* __restrict__ sboxes, unsigned* __restrict__ Tcol,
                        unsigned long long* __restrict__ diagR){
    int i = blockIdx.x;
    int lane = threadIdx.x;
    int gi = i >> 6;
    float cxi = sboxes[i*12+1], cyi = sboxes[i*12+2], wi = sboxes[i*12+3], hi = sboxes[i*12+4];
    float x1i = cxi - wi/2.0f, y1i = cyi - hi/2.0f, x2i = cxi + wi/2.0f, y2i = cyi + hi/2.0f;
    float ari = fmaxf(x2i-x1i, 0.f) * fmaxf(y2i-y1i, 0.f);
    unsigned colbits = 0u;
    for (int c=0; c<24; c++){
        int j = c*64 + lane;
        float cxj = sboxes[j*12+1], cyj = sboxes[j*12+2], wj = sboxes[j*12+3], hj = sboxes[j*12+4];
        float x1j = cxj - wj/2.0f, y1j = cyj - hj/2.0f, x2j = cxj + wj/2.0f, y2j = cyj + hj/2.0f;
        float arj = fmaxf(x2j-x1j, 0.f) * fmaxf(y2j-y1j, 0.f);
        float ix = fmaxf(0.f, fminf(x2i, x2j) - fmaxf(x1i, x1j));
        float iy = fmaxf(0.f, fminf(y2i, y2j) - fmaxf(y1i, y1j));
        float inter = ix * iy;
        float iou = inter / fmaxf(fminf(ari, arj), 1e-9f);
        bool sb = (iou > 0.7f) && (j > i);
        colbits |= sb ? (1u << c) : 0u;
    }
    Tcol[(size_t)i*64 + lane] = colbits;
    // row mask within the diagonal tile, one ballot (replaces atomicOr'd column masks)
    unsigned long long rowbits = __ballot(((colbits >> gi) & 1u) != 0u);
    if (lane == 0) diagR[i] = rowbits;
}

__device__ __forceinline__ unsigned long long readlane64(unsigned long long v, int i){
    unsigned lo = (unsigned)__builtin_amdgcn_readlane((int)(unsigned)v, i);
    unsigned hi = (unsigned)__builtin_amdgcn_readlane((int)(unsigned)(v >> 32), i);
    return ((unsigned long long)hi << 32) | (unsigned long long)lo;
}

// Greedy NMS scan, fully pipelined:
//  - ALL 4 waves run the resolve chain redundantly (identical inputs => identical
//    results), so no broadcast barrier and no idle waves.
//  - resolve is a PURE SCALAR chain: s_ff1 + v_readlane + s_and per kept box
//    (~20 cyc/iter) instead of the VALU->ballot->SALU round-trip (~60-80 cyc/iter).
//  - Tcol row loads for tile g+1 are unconditional and issued while tile g is
//    merged + tile g+1 resolved (LLC latency hidden).
//  - partial[] double-buffered => ONE barrier per tile.
__global__ void k_nms_out(const float* __restrict__ sboxes, const unsigned long long* __restrict__ vwords,
                          const unsigned long long* __restrict__ diagR, const unsigned* __restrict__ Tcol,
                          float* __restrict__ out){
    __shared__ unsigned long long keepw[24];
    __shared__ unsigned partial[2][4][64];
    int t = threadIdx.x;
    int wv = t >> 6, lane = t & 63;
    unsigned SS = 0u;      // bit g = box g*64+lane suppressed; identical in all waves
    unsigned long long rowR = diagR[lane];      // lane l: boxes suppressed by box g*64+l in-tile
    unsigned long long vcur = vwords[0];
    unsigned rows[16];
    {
        const unsigned* b0 = Tcol + (size_t)(wv*16)*64 + lane;
        #pragma unroll
        for (int i=0;i<16;i++) rows[i] = b0[i*64];
    }
    for (int g = 0; g < 24; g++){
        // prefetch next tile's diag-row/valid early (in flight across resolve+merge+barrier)
        unsigned long long Rnext = (g < 23) ? diagR[(g+1)*64 + lane] : 0ull;
        unsigned long long vnext = (g < 23) ? vwords[g+1] : 0ull;
        // resolve tile g (redundant in every wave): scalar greedy chain
        bool live = (((vcur >> lane) & 1ull) != 0ull) && (((SS >> g) & 1u) == 0u);
        unsigned long long pend = __ballot(live);
        unsigned long long keptW = 0ull;
        while (pend){
            int i = __ffsll((long long)pend) - 1;
            keptW |= 1ull << i;
            unsigned long long sup = readlane64(rowR, i);
            unsigned long long above = (i == 63) ? 0ull : (~0ull << (i+1));
            pend = pend & ~sup & above;
        }
        if (t == 0) keepw[g] = keptW;
        // mask current rows by kept bits, reduce to this wave's partial
        unsigned kbits = (unsigned)((keptW >> (wv*16)) & 0xFFFFull);   // wave-uniform
        unsigned acc = 0u;
        #pragma unroll
        for (int i=0;i<16;i++) acc |= (0u - ((kbits >> i) & 1u)) & rows[i];
        // issue next tile's row loads now (in flight across barrier+merge+resolve)
        if (g < 23){
            const unsigned* nb = Tcol + (size_t)((g+1)*64 + wv*16)*64 + lane;
            #pragma unroll
            for (int i=0;i<16;i++) rows[i] = nb[i*64];
        }
        partial[g & 1][wv][lane] = acc;
        __syncthreads();
        SS |= partial[g & 1][0][lane] | partial[g & 1][1][lane]
            | partial[g & 1][2][lane] | partial[g & 1][3][lane];
        rowR = Rnext; vcur = vnext;
    }
    for (int e=t; e<NBOX*9; e+=256){
        int r = e / 9;
        int c = e - r*9;
        bool kp = ((keepw[r >> 6] >> (r & 63)) & 1ull) != 0ull;
        out[e] = kp ? sboxes[r*12 + c] : 0.f;
    }
}

extern "C" void kernel_launch(void* const* d_in, const int* in_sizes, int n_in,
                              void* d_out, int out_size, void* d_ws, size_t ws_size,
                              hipStream_t stream){
    const float* o13 = (const float*)d_in[0];
    const float* o26 = (const float*)d_in[1];
    const float* o52 = (const float*)d_in[2];
    const float* a13 = (const float*)d_in[3];
    const float* a26 = (const float*)d_in[4];
    const float* a52 = (const float*)d_in[5];
    char* ws = (char*)d_ws;
    unsigned long long* cand  = (unsigned long long*)(ws);              // TOTCELL*8 = 2,725,632
    unsigned* Tcol            = (unsigned*)(ws);                        // 393,216 — ALIASES cand (cand dead after k_classify)
    int* hist                 = (int*)(ws + 2752512);                   // 12,288
    int* cnt                  = (int*)(ws + 2801664);                   // 256
    unsigned long long* sel   = (unsigned long long*)(ws + 2801920);    // 12,288
    unsigned long long* stash = (unsigned long long*)(ws + 2814208);    // 24,576
    float* boxes              = (float*)(ws + 2838784);                 // 73,728
    float* sboxes             = (float*)(ws + 2912512);                 // 73,728
    unsigned long long* vw    = (unsigned long long*)(ws + 2986240);    // 256
    unsigned long long* diagR = (unsigned long long*)(ws + 2986496);    // 12,288 (end ~3.0 MB)
    float* out = (float*)d_out;

    k_init    <<<12, 256, 0, stream>>>(hist, cnt);
    k_score   <<<(TOTCELL + 255)/256, 256, 0, stream>>>(o13, o26, o52, cand, hist);
    k_cutoff  <<<3, NBINS, 0, stream>>>(hist, cnt);
    k_classify<<<(TOTCELL + 255)/256, 256, 0, stream>>>(cand, cnt, sel, stash);
    k_finalize<<<3, 1024, 0, stream>>>(cnt, sel, stash);
    k_decode  <<<NBOX/4, 256, 0, stream>>>(o13, o26, o52, a13, a26, a52, sel, boxes);
    k_sort    <<<1, 1024, 0, stream>>>(sel, boxes, sboxes, vw);
    k_masks   <<<NBOX, 64, 0, stream>>>(sboxes, Tcol, diagR);
    k_nms_out <<<1, 256, 0, stream>>>(sboxes, vw, diagR, Tcol, out);
}

// Round 2
// 260.540 us; speedup vs baseline: 1.1835x; 1.1473x over previous
//
#include <hip/hip_runtime.h>
#include <stdint.h>

#define KPS 512
#define NBOX 1536
#define NBINS 1024

// scale cell counts: 32*H*H*3
#define S13 16224
#define S26 64896
#define S52 259584
#define TOTCELL 340704

__device__ __forceinline__ uint32_t f2u(float x){ union{float f;uint32_t u;}v; v.f=x; return v.u; }
__device__ __forceinline__ float u2f(uint32_t x){ union{float f;uint32_t u;}v; v.u=x; return v.f; }

__device__ __forceinline__ int binOf(float s){
    int b = (int)((s - 0.6f) * 2560.0f);    // 1024 bins over (0.6, 1.0)
    if (b < 0) b = 0;
    if (b > NBINS-1) b = NBINS-1;
    return b;
}

// counters: [3..5] abovePos, [6..8] stashCnt, [9..11] cutoffB, [12..14] aboveCount
__global__ void k_init(int* hist, int* cnt){
    int id = blockIdx.x*256 + threadIdx.x;
    if (id < 3*NBINS) hist[id] = 0;
    if (id < 32) cnt[id] = 0;
}

// Sparse candidate slots: cand[id] = key or 0. No wave-stalling atomics.
__global__ void k_score(const float* __restrict__ o13, const float* __restrict__ o26,
                        const float* __restrict__ o52,
                        unsigned long long* __restrict__ cand, int* __restrict__ hist){
    int id = blockIdx.x*256 + threadIdx.x;
    if (id >= TOTCELL) return;
    int scale, idl, H;
    const float* src;
    if (id < S13)            { scale=0; idl=id;            H=13; src=o13; }
    else if (id < S13+S26)   { scale=1; idl=id-S13;        H=26; src=o26; }
    else                     { scale=2; idl=id-(S13+S26);  H=52; src=o52; }
    int HW = H*H;
    // plane-major thread mapping for coalescing: idl = p*HW + hw, p = n*3 + a
    int p  = idl / HW;
    int hw = idl - p*HW;
    int n  = p / 3;
    int a  = p - n*3;
    int cidx = (n*HW + hw)*3 + a;       // reference flat cell index
    float x = src[(size_t)(n*255 + a*85)*HW + hw];
    float s = (float)(1.0 / (1.0 + exp(-(double)x)));   // correctly-rounded f32 sigmoid
    unsigned long long key = 0ull;
    if (s > 0.6f){
        key = ((unsigned long long)f2u(s) << 20)
            | ((unsigned long long)(2-scale) << 18)
            | (unsigned long long)(262143 - cidx);
        atomicAdd(&hist[scale*NBINS + binOf(s)], 1);   // fire-and-forget, spread bins
    }
    cand[id] = key;
}

__global__ void __launch_bounds__(1024) k_cutoff(const int* __restrict__ hist, int* __restrict__ cnt){
    int s = blockIdx.x, t = threadIdx.x;
    __shared__ int suf[NBINS];
    int h = hist[s*NBINS + t];
    suf[t] = h; __syncthreads();
    for (int d=1; d<NBINS; d<<=1){
        int v = (t+d < NBINS) ? suf[t+d] : 0;
        __syncthreads();
        suf[t] += v;
        __syncthreads();
    }
    int total = suf[0];
    int A = (t < NBINS-1) ? suf[t+1] : 0;   // count strictly above bin t
    if (t == 0 && total < KPS){ cnt[9+s] = -1; cnt[12+s] = total; }
    if (A < KPS && A + h >= KPS){ cnt[9+s] = t; cnt[12+s] = A; }
}

__global__ void k_classify(const unsigned long long* __restrict__ cand, int* __restrict__ cnt,
                           unsigned long long* __restrict__ sel, unsigned long long* __restrict__ stash){
    int id = blockIdx.x*256 + threadIdx.x;
    unsigned long long key = (id < TOTCELL) ? cand[id] : 0ull;
    bool live = (key != 0ull);
    int scale = live ? (2 - (int)((key >> 18) & 3ull)) : 0;
    int bin = live ? binOf(u2f((uint32_t)(key >> 20))) : -2;
    int B = cnt[9+scale];
    int lane = threadIdx.x & 63;
    unsigned long long lanebit_m1 = (lane == 63) ? ~0ull >> 1 : ((1ull << lane) - 1ull);
    bool above = live && (bin > B);
    bool bound = live && (bin == B);
    // wave-aggregate both counters (waves may straddle scales; loop scales)
    #pragma unroll
    for (int sc = 0; sc < 3; sc++){
        unsigned long long ma = __ballot(above && scale == sc);
        if (ma){
            int leader = __ffsll((long long)ma) - 1;
            int base = 0;
            if (lane == leader) base = atomicAdd(&cnt[3+sc], __popcll(ma));
            base = __shfl(base, leader);
            if (above && scale == sc)
                sel[sc*KPS + base + __popcll(ma & lanebit_m1)] = key;
        }
        unsigned long long mb = __ballot(bound && scale == sc);
        if (mb){
            int leader = __ffsll((long long)mb) - 1;
            int base = 0;
            if (lane == leader) base = atomicAdd(&cnt[6+sc], __popcll(mb));
            base = __shfl(base, leader);
            if (bound && scale == sc){
                int q = base + __popcll(mb & lanebit_m1);
                if (q < 1024) stash[sc*1024 + q] = key;
            }
        }
    }
}

// Sort the boundary-bin stash (desc), splice top-`need` after the above-cutoff
// entries, then fully sort the 512-entry group in LDS (desc). The group is
// written back SORTED, so the global sort collapses to a 3-way merge by rank.
__global__ void __launch_bounds__(1024) k_finalize(const int* __restrict__ cnt,
                           unsigned long long* __restrict__ sel, const unsigned long long* __restrict__ stash){
    int s = blockIdx.x, t = threadIdx.x;
    __shared__ unsigned long long sk[1024];
    __shared__ unsigned long long gbuf[512];
    int sc = cnt[6+s]; if (sc > 1024) sc = 1024;
    sk[t] = (t < sc) ? stash[s*1024 + t] : 0ull;
    __syncthreads();
    for (int k=2; k<=1024; k<<=1)
        for (int j=k>>1; j>0; j>>=1){
            int ixj = t ^ j;
            if (ixj > t){
                bool up = ((t & k) == 0);   // descending overall
                unsigned long long a = sk[t], b = sk[ixj];
                if (up ? (a < b) : (a > b)){ sk[t] = b; sk[ixj] = a; }
            }
            __syncthreads();
        }
    int above = cnt[12+s];
    int need = KPS - above; if (need < 0) need = 0;
    int m = (need < sc) ? need : sc;
    if (t < 512) gbuf[t] = (t < above) ? sel[s*KPS + t]
                          : ((t - above) < m ? sk[t - above] : 0ull);
    __syncthreads();
    for (int k=2; k<=512; k<<=1)
        for (int j=k>>1; j>0; j>>=1){
            if (t < 512){
                int ixj = t ^ j;
                if (ixj > t){
                    bool up = ((t & k) == 0);   // descending overall
                    unsigned long long a = gbuf[t], b = gbuf[ixj];
                    if (up ? (a < b) : (a > b)){ gbuf[t] = b; gbuf[ixj] = a; }
                }
            }
            __syncthreads();
        }
    if (t < 512) sel[s*KPS + t] = gbuf[t];
}

__global__ void k_decode(const float* __restrict__ o13, const float* __restrict__ o26,
                         const float* __restrict__ o52,
                         const float* __restrict__ a13, const float* __restrict__ a26,
                         const float* __restrict__ a52,
                         const unsigned long long* __restrict__ sel, float* __restrict__ boxes){
    int gtid = blockIdx.x*256 + threadIdx.x;
    int b = gtid >> 6;
    int lane = threadIdx.x & 63;
    if (b >= NBOX) return;
    unsigned long long key = sel[b];
    float* row = boxes + b*12;
    if ((key >> 20) == 0ull){           // sentinel
        if (lane < 9) row[lane] = 0.f;
        return;
    }
    int scale = 2 - (int)((key >> 18) & 3ull);
    int cidx  = 262143 - (int)(key & 0x3FFFFull);
    uint32_t sbits = (uint32_t)(key >> 20);
    const float* src; const float* anch; int H; float tt;
    if (scale == 0){ src=o13; anch=a13; H=13; tt=32.f; }
    else if (scale == 1){ src=o26; anch=a26; H=26; tt=16.f; }
    else { src=o52; anch=a52; H=52; tt=8.f; }
    int HW = H*H;
    int a  = cidx % 3;
    int hw = (cidx/3) % HW;
    int n  = cidx / (3*HW);
    int hh = hw / H;
    int ww = hw - hh*H;
    const float* cellbase = src + (size_t)(n*255 + a*85)*HW + hw;
    // argmax over 80 classes, tie -> lowest class index
    float bv = cellbase[(size_t)(5 + lane)*HW];
    int bi = lane;
    if (lane < 16){
        float v2 = cellbase[(size_t)(69 + lane)*HW];
        if (v2 > bv){ bv = v2; bi = 64 + lane; }
    }
    #pragma unroll
    for (int off=32; off; off>>=1){
        float vo = __shfl_xor(bv, off);
        int io = __shfl_xor(bi, off);
        if (vo > bv || (vo == bv && io < bi)){ bv = vo; bi = io; }
    }
    if (lane == 0){
        float v1 = cellbase[(size_t)1*HW];
        float v2 = cellbase[(size_t)2*HW];
        float v3 = cellbase[(size_t)3*HW];
        float v4 = cellbase[(size_t)4*HW];
        float cx = ((float)ww + v1) * tt / 416.0f;
        float cy = ((float)hh + v2) * tt / 416.0f;
        float e3 = (float)exp((double)v3);
        float e4 = (float)exp((double)v4);
        float bw = anch[a*2+0] * e3 / 416.0f;
        float bh = anch[a*2+1] * e4 / 416.0f;
        row[0] = (float)n;  row[1] = cx; row[2] = cy; row[3] = bw; row[4] = bh;
        row[5] = u2f(sbits); row[6] = (float)bi; row[7] = (float)hh; row[8] = (float)ww;
    }
}

// 3-way merge by rank: each group is sorted desc; element rank = own index +
// binary-search ranks into the other two groups. Nonzero keys are globally
// unique (scale bits embedded); ties (sentinel zeros) broken group-asc which
// reproduces the old full-sort order exactly. vwords is an analytic prefix
// mask since valid keys sort to a contiguous prefix.
__global__ void __launch_bounds__(256) k_merge(const int* __restrict__ cnt,
                       const unsigned long long* __restrict__ sel,
                       const float* __restrict__ boxes, float* __restrict__ sboxes,
                       unsigned long long* __restrict__ vwords){
    __shared__ unsigned long long keys[NBOX];
    int t = threadIdx.x, b = blockIdx.x;
    for (int r=t; r<NBOX; r+=256) keys[r] = sel[r];
    __syncthreads();
    int p = b*256 + t;
    int gph = p >> 9;
    int i  = p & 511;
    unsigned long long k = keys[p];
    int rank = i;
    #pragma unroll
    for (int gg=0; gg<3; gg++){
        if (gg == gph) continue;
        const unsigned long long* a = keys + gg*512;
        bool geq = (gg < gph);          // equal keys (zeros): earlier group wins
        int lo = 0, hi = 512;
        while (lo < hi){
            int mid = (lo + hi) >> 1;
            bool adv = geq ? (a[mid] >= k) : (a[mid] > k);
            if (adv) lo = mid + 1; else hi = mid;
        }
        rank += lo;
    }
    bool valid = (k != 0ull);
    const float* srcr = boxes + p*12;
    float* dst = sboxes + rank*12;
    #pragma unroll
    for (int c=0; c<9; c++) dst[c] = valid ? srcr[c] : 0.f;
    if (b == 0 && t < 24){
        int nv = 0;
        #pragma unroll
        for (int s2=0; s2<3; s2++){
            int above = cnt[12+s2];
            int sc2 = cnt[6+s2]; if (sc2 > 1024) sc2 = 1024;
            int need = KPS - above; if (need < 0) need = 0;
            int m = (need < sc2) ? need : sc2;
            nv += above + m;
        }
        int rem = nv - t*64;
        vwords[t] = rem >= 64 ? ~0ull : (rem <= 0 ? 0ull : ((1ull << rem) - 1ull));
    }
}

// Column-sliced suppression matrix: Tcol[i*64 + j] bit c = sup(i, c*64+j).
// Diagonal-tile ROW masks: diagR[i] bit j = sup(i, gi*64+j) where gi = i>>6.
__global__ void k_masks(const float* __restrict__ sboxes, unsigned* __restrict__ Tcol,
                        unsigned long long* __restrict__ diagR){
    int i = blockIdx.x;
    int lane = threadIdx.x;
    int gi = i >> 6;
    float cxi = sboxes[i*12+1], cyi = sboxes[i*12+2], wi = sboxes[i*12+3], hi = sboxes[i*12+4];
    float x1i = cxi - wi/2.0f, y1i = cyi - hi/2.0f, x2i = cxi + wi/2.0f, y2i = cyi + hi/2.0f;
    float ari = fmaxf(x2i-x1i, 0.f) * fmaxf(y2i-y1i, 0.f);
    unsigned colbits = 0u;
    for (int c=0; c<24; c++){
        int j = c*64 + lane;
        float cxj = sboxes[j*12+1], cyj = sboxes[j*12+2], wj = sboxes[j*12+3], hj = sboxes[j*12+4];
        float x1j = cxj - wj/2.0f, y1j = cyj - hj/2.0f, x2j = cxj + wj/2.0f, y2j = cyj + hj/2.0f;
        float arj = fmaxf(x2j-x1j, 0.f) * fmaxf(y2j-y1j, 0.f);
        float ix = fmaxf(0.f, fminf(x2i, x2j) - fmaxf(x1i, x1j));
        float iy = fmaxf(0.f, fminf(y2i, y2j) - fmaxf(y1i, y1j));
        float inter = ix * iy;
        float iou = inter / fmaxf(fminf(ari, arj), 1e-9f);
        bool sb = (iou > 0.7f) && (j > i);
        colbits |= sb ? (1u << c) : 0u;
    }
    Tcol[(size_t)i*64 + lane] = colbits;
    // row mask within the diagonal tile, one ballot
    unsigned long long rowbits = __ballot(((colbits >> gi) & 1u) != 0u);
    if (lane == 0) diagR[i] = rowbits;
}

__device__ __forceinline__ unsigned long long readlane64(unsigned long long v, int i){
    unsigned lo = (unsigned)__builtin_amdgcn_readlane((int)(unsigned)v, i);
    unsigned hi = (unsigned)__builtin_amdgcn_readlane((int)(unsigned)(v >> 32), i);
    return ((unsigned long long)hi << 32) | (unsigned long long)lo;
}

// Greedy NMS scan:
//  - ALL 4 waves run the resolve redundantly (identical inputs => identical results).
//  - SUPPRESSOR-SKIP resolve: rowR[l] only has bits > l, so
//    Z = ballot(live && (rowR & pend)) is exactly the set of lanes that can
//    change the outcome. The scalar chain visits only Z (typically 0-3 lanes),
//    checking each is still kept at its turn — exact greedy semantics, O(#suppressors)
//    instead of O(#kept).
//  - Tcol row loads for tile g+1 issued while tile g is merged (latency hidden).
//  - partial[] double-buffered => ONE barrier per tile.
__global__ void k_nms_out(const float* __restrict__ sboxes, const unsigned long long* __restrict__ vwords,
                          const unsigned long long* __restrict__ diagR, const unsigned* __restrict__ Tcol,
                          float* __restrict__ out){
    __shared__ unsigned long long keepw[24];
    __shared__ unsigned partial[2][4][64];
    int t = threadIdx.x;
    int wv = t >> 6, lane = t & 63;
    unsigned SS = 0u;      // bit g = box g*64+lane suppressed; identical in all waves
    unsigned long long rowR = diagR[lane];
    unsigned long long vcur = vwords[0];
    unsigned rows[16];
    {
        const unsigned* b0 = Tcol + (size_t)(wv*16)*64 + lane;
        #pragma unroll
        for (int i=0;i<16;i++) rows[i] = b0[i*64];
    }
    for (int g = 0; g < 24; g++){
        // prefetch next tile's diag-row/valid early
        unsigned long long Rnext = (g < 23) ? diagR[(g+1)*64 + lane] : 0ull;
        unsigned long long vnext = (g < 23) ? vwords[g+1] : 0ull;
        // resolve tile g: suppressor-skip greedy chain
        bool live = (((vcur >> lane) & 1ull) != 0ull) && (((SS >> g) & 1u) == 0u);
        unsigned long long pend = __ballot(live);
        unsigned long long Z = __ballot(live && ((rowR & pend) != 0ull));
        unsigned long long kept = pend;
        unsigned long long iter = Z;
        while (iter){
            int i = __ffsll((long long)iter) - 1;
            iter &= iter - 1ull;
            if ((kept >> i) & 1ull){
                unsigned long long sup = readlane64(rowR, i);   // only bits > i
                kept &= ~sup;
                iter &= ~sup;
            }
        }
        if (t == 0) keepw[g] = kept;
        // mask current rows by kept bits, reduce to this wave's partial
        unsigned kbits = (unsigned)((kept >> (wv*16)) & 0xFFFFull);   // wave-uniform
        unsigned acc = 0u;
        #pragma unroll
        for (int i=0;i<16;i++) acc |= (0u - ((kbits >> i) & 1u)) & rows[i];
        // issue next tile's row loads now (in flight across barrier+merge+resolve)
        if (g < 23){
            const unsigned* nb = Tcol + (size_t)((g+1)*64 + wv*16)*64 + lane;
            #pragma unroll
            for (int i=0;i<16;i++) rows[i] = nb[i*64];
        }
        partial[g & 1][wv][lane] = acc;
        __syncthreads();
        SS |= partial[g & 1][0][lane] | partial[g & 1][1][lane]
            | partial[g & 1][2][lane] | partial[g & 1][3][lane];
        rowR = Rnext; vcur = vnext;
    }
    for (int e=t; e<NBOX*9; e+=256){
        int r = e / 9;
        int c = e - r*9;
        bool kp = ((keepw[r >> 6] >> (r & 63)) & 1ull) != 0ull;
        out[e] = kp ? sboxes[r*12 + c] : 0.f;
    }
}

extern "C" void kernel_launch(void* const* d_in, const int* in_sizes, int n_in,
                              void* d_out, int out_size, void* d_ws, size_t ws_size,
                              hipStream_t stream){
    const float* o13 = (const float*)d_in[0];
    const float* o26 = (const float*)d_in[1];
    const float* o52 = (const float*)d_in[2];
    const float* a13 = (const float*)d_in[3];
    const float* a26 = (const float*)d_in[4];
    const float* a52 = (const float*)d_in[5];
    char* ws = (char*)d_ws;
    unsigned long long* cand  = (unsigned long long*)(ws);              // TOTCELL*8 = 2,725,632
    unsigned* Tcol            = (unsigned*)(ws);                        // 393,216 — ALIASES cand (cand dead after k_classify)
    int* hist                 = (int*)(ws + 2752512);                   // 12,288
    int* cnt                  = (int*)(ws + 2801664);                   // 256
    unsigned long long* sel   = (unsigned long long*)(ws + 2801920);    // 12,288
    unsigned long long* stash = (unsigned long long*)(ws + 2814208);    // 24,576
    float* boxes              = (float*)(ws + 2838784);                 // 73,728
    float* sboxes             = (float*)(ws + 2912512);                 // 73,728
    unsigned long long* vw    = (unsigned long long*)(ws + 2986240);    // 256
    unsigned long long* diagR = (unsigned long long*)(ws + 2986496);    // 12,288 (end ~3.0 MB)
    float* out = (float*)d_out;

    k_init    <<<12, 256, 0, stream>>>(hist, cnt);
    k_score   <<<(TOTCELL + 255)/256, 256, 0, stream>>>(o13, o26, o52, cand, hist);
    k_cutoff  <<<3, NBINS, 0, stream>>>(hist, cnt);
    k_classify<<<(TOTCELL + 255)/256, 256, 0, stream>>>(cand, cnt, sel, stash);
    k_finalize<<<3, 1024, 0, stream>>>(cnt, sel, stash);
    k_decode  <<<NBOX/4, 256, 0, stream>>>(o13, o26, o52, a13, a26, a52, sel, boxes);
    k_merge   <<<6, 256, 0, stream>>>(cnt, sel, boxes, sboxes, vw);
    k_masks   <<<NBOX, 64, 0, stream>>>(sboxes, Tcol, diagR);
    k_nms_out <<<1, 256, 0, stream>>>(sboxes, vw, diagR, Tcol, out);
}

// Round 4
// 246.633 us; speedup vs baseline: 1.2502x; 1.0564x over previous
//
#include <hip/hip_runtime.h>
#include <stdint.h>

#define KPS 512
#define NBOX 1536
#define NBINS 1024

// scale cell counts: 32*H*H*3
#define S13 16224
#define S26 64896
#define S52 259584
#define TOTCELL 340704

__device__ __forceinline__ uint32_t f2u(float x){ union{float f;uint32_t u;}v; v.f=x; return v.u; }
__device__ __forceinline__ float u2f(uint32_t x){ union{float f;uint32_t u;}v; v.u=x; return v.f; }

__device__ __forceinline__ int binOf(float s){
    int b = (int)((s - 0.6f) * 2560.0f);    // 1024 bins over (0.6, 1.0)
    if (b < 0) b = 0;
    if (b > NBINS-1) b = NBINS-1;
    return b;
}

// Score pass: one 4-byte sigmoid-bits slot per cell (0 if below threshold).
// No atomics, no pre-zeroed state needed anywhere upstream.
__global__ void k_score(const float* __restrict__ o13, const float* __restrict__ o26,
                        const float* __restrict__ o52, unsigned* __restrict__ scr){
    int id = blockIdx.x*256 + threadIdx.x;
    if (id >= TOTCELL) return;
    int idl, H;
    const float* src;
    if (id < S13)            { idl=id;            H=13; src=o13; }
    else if (id < S13+S26)   { idl=id-S13;        H=26; src=o26; }
    else                     { idl=id-(S13+S26);  H=52; src=o52; }
    int HW = H*H;
    // plane-major thread mapping for coalescing: idl = p*HW + hw, p = n*3 + a
    int p  = idl / HW;
    int hw = idl - p*HW;
    int n  = p / 3;
    int a  = p - n*3;
    float x = src[(size_t)(n*255 + a*85)*HW + hw];
    float s = (float)(1.0 / (1.0 + exp(-(double)x)));   // correctly-rounded f32 sigmoid
    scr[id] = (s > 0.6f) ? f2u(s) : 0u;
}

// Fused cutoff+classify+finalize: one block per scale.
//  - LDS histogram over the scale's scr slice (uint4 loads)
//  - suffix scan -> cutoff bin B (identical logic to old k_cutoff)
//  - second scan partitions candidates into LDS above[]/stash[] lists,
//    reconstructing the 64-bit key from (sbits, index)
//  - rank sort of the union (keys unique & nonzero): top-Nsel == above + top-m(stash)
//    because bins are monotone in score -> every above-key > every stash-key.
//  - writes sel[scale] sorted desc + zero sentinels, cnt[scale] = Nsel
template<int H, int SCALE, int OFF, int LEN>
__device__ __forceinline__ void select_impl(const unsigned* __restrict__ scr,
        unsigned long long* __restrict__ sel, int* __restrict__ cnt,
        int* histL, unsigned long long* un, int* sB, int* scA, int* scS){
    constexpr int HW = H*H;
    constexpr int N4 = LEN/4;           // all LEN divisible by 4
    int t = threadIdx.x;
    histL[t] = 0;
    if (t == 0){ *scA = 0; *scS = 0; }
    __syncthreads();
    const uint4* v4 = reinterpret_cast<const uint4*>(scr + OFF);
    for (int i = t; i < N4; i += 1024){
        uint4 u = v4[i];
        if (u.x) atomicAdd(&histL[binOf(u2f(u.x))], 1);
        if (u.y) atomicAdd(&histL[binOf(u2f(u.y))], 1);
        if (u.z) atomicAdd(&histL[binOf(u2f(u.z))], 1);
        if (u.w) atomicAdd(&histL[binOf(u2f(u.w))], 1);
    }
    __syncthreads();
    int h = histL[t];
    for (int d = 1; d < NBINS; d <<= 1){    // in-place suffix scan
        int v = (t + d < NBINS) ? histL[t + d] : 0;
        __syncthreads();
        histL[t] += v;
        __syncthreads();
    }
    int total = histL[0];
    int Aab = (t < NBINS-1) ? histL[t+1] : 0;   // count strictly above bin t
    if (t == 0 && total < KPS) *sB = -1;
    if (Aab < KPS && Aab + h >= KPS) *sB = t;   // exactly one thread when total>=KPS
    __syncthreads();
    int B = *sB;
    for (int i = t; i < N4; i += 1024){
        uint4 u = v4[i];
        #pragma unroll
        for (int c = 0; c < 4; c++){
            unsigned sb = (c==0)?u.x:(c==1)?u.y:(c==2)?u.z:u.w;
            if (!sb) continue;
            int bin = binOf(u2f(sb));
            if (bin < B) continue;
            int idx = i*4 + c;                    // in-scale linear id
            int p  = idx / HW;                    // constexpr divisor -> magic mul
            int hw = idx - p*HW;
            int n  = p / 3;
            int a  = p - n*3;
            int cidx = (n*HW + hw)*3 + a;
            unsigned long long key = ((unsigned long long)sb << 20)
                | ((unsigned long long)(2-SCALE) << 18)
                | (unsigned long long)(262143 - cidx);
            if (bin > B){
                int pos = atomicAdd(scA, 1);      // < 512 guaranteed by cutoff def
                un[pos] = key;
            } else {
                int pos = atomicAdd(scS, 1);
                if (pos < 1024) un[512 + pos] = key;   // same clamp as old stash
            }
        }
    }
    __syncthreads();
    int cA = *scA;
    int cSk = *scS; if (cSk > 1024) cSk = 1024;
    int need = KPS - cA; if (need < 0) need = 0;
    int m = (need < cSk) ? need : cSk;
    int Nsel = cA + m;
    int E = cA + cSk;
    // rank sort: all union keys unique & nonzero -> rank = #{greater}
    for (int e = t; e < E; e += 1024){
        unsigned long long k = (e < cA) ? un[e] : un[512 + e - cA];
        int rank = 0;
        for (int q = 0; q < cA; q++)  rank += (un[q] > k) ? 1 : 0;
        for (int q = 0; q < cSk; q++) rank += (un[512 + q] > k) ? 1 : 0;
        if (rank < Nsel) sel[SCALE*KPS + rank] = k;
    }
    if (t < KPS && t >= Nsel) sel[SCALE*KPS + t] = 0ull;   // sentinels
    if (t == 0) cnt[SCALE] = Nsel;
}

__global__ void __launch_bounds__(1024) k_select(const unsigned* __restrict__ scr,
                        unsigned long long* __restrict__ sel, int* __restrict__ cnt){
    __shared__ int histL[NBINS];
    __shared__ unsigned long long un[1536];     // [0,512) above, [512,1536) stash
    __shared__ int sB, scA, scS;
    int s = blockIdx.x;
    if (s == 0)      select_impl<13,0,0,        S13>(scr, sel, cnt, histL, un, &sB, &scA, &scS);
    else if (s == 1) select_impl<26,1,S13,      S26>(scr, sel, cnt, histL, un, &sB, &scA, &scS);
    else             select_impl<52,2,S13+S26,  S52>(scr, sel, cnt, histL, un, &sB, &scA, &scS);
}

// Fused decode+merge: stage all sel keys in LDS, compute each box's global rank
// (wave scan + shuffle reduce; keys unique, zeros tie-broken by position -> same
// permutation the old merge produced), decode, and write straight to sboxes[rank].
// Block 0 also emits the analytic vwords prefix mask from cnt.
__global__ void k_decode_merge(const float* __restrict__ o13, const float* __restrict__ o26,
                         const float* __restrict__ o52,
                         const float* __restrict__ a13, const float* __restrict__ a26,
                         const float* __restrict__ a52,
                         const unsigned long long* __restrict__ sel, const int* __restrict__ cnt,
                         float* __restrict__ sboxes, unsigned long long* __restrict__ vwords){
    __shared__ unsigned long long sk[NBOX];
    int t = threadIdx.x;
    for (int r = t; r < NBOX; r += 256) sk[r] = sel[r];
    __syncthreads();
    int wv = t >> 6, lane = t & 63;
    int b = blockIdx.x*4 + wv;
    unsigned long long key = sk[b];
    int pc = 0;
    for (int q = lane; q < NBOX; q += 64){
        unsigned long long kq = sk[q];
        pc += (kq > key || (kq == key && q < b)) ? 1 : 0;
    }
    #pragma unroll
    for (int off = 32; off; off >>= 1) pc += __shfl_xor(pc, off);
    int rank = pc;                       // permutation of [0,NBOX)
    float* row = sboxes + rank*12;
    if ((key >> 20) == 0ull){            // sentinel
        if (lane < 9) row[lane] = 0.f;
    } else {
        int scale = 2 - (int)((key >> 18) & 3ull);
        int cidx  = 262143 - (int)(key & 0x3FFFFull);
        uint32_t sbits = (uint32_t)(key >> 20);
        const float* src; const float* anch; int H; float tt;
        if (scale == 0){ src=o13; anch=a13; H=13; tt=32.f; }
        else if (scale == 1){ src=o26; anch=a26; H=26; tt=16.f; }
        else { src=o52; anch=a52; H=52; tt=8.f; }
        int HW = H*H;
        int a  = cidx % 3;
        int hw = (cidx/3) % HW;
        int n  = cidx / (3*HW);
        int hh = hw / H;
        int ww = hw - hh*H;
        const float* cellbase = src + (size_t)(n*255 + a*85)*HW + hw;
        // argmax over 80 classes, tie -> lowest class index
        float bv = cellbase[(size_t)(5 + lane)*HW];
        int bi = lane;
        if (lane < 16){
            float v2 = cellbase[(size_t)(69 + lane)*HW];
            if (v2 > bv){ bv = v2; bi = 64 + lane; }
        }
        #pragma unroll
        for (int off=32; off; off>>=1){
            float vo = __shfl_xor(bv, off);
            int io = __shfl_xor(bi, off);
            if (vo > bv || (vo == bv && io < bi)){ bv = vo; bi = io; }
        }
        if (lane == 0){
            float v1 = cellbase[(size_t)1*HW];
            float v2 = cellbase[(size_t)2*HW];
            float v3 = cellbase[(size_t)3*HW];
            float v4 = cellbase[(size_t)4*HW];
            float cx = ((float)ww + v1) * tt / 416.0f;
            float cy = ((float)hh + v2) * tt / 416.0f;
            float e3 = (float)exp((double)v3);
            float e4 = (float)exp((double)v4);
            float bw = anch[a*2+0] * e3 / 416.0f;
            float bh = anch[a*2+1] * e4 / 416.0f;
            row[0] = (float)n;  row[1] = cx; row[2] = cy; row[3] = bw; row[4] = bh;
            row[5] = u2f(sbits); row[6] = (float)bi; row[7] = (float)hh; row[8] = (float)ww;
        }
    }
    if (blockIdx.x == 0 && t < 24){
        int nv = cnt[0] + cnt[1] + cnt[2];   // valid keys sort to a contiguous prefix
        int rem = nv - t*64;
        vwords[t] = rem >= 64 ? ~0ull : (rem <= 0 ? 0ull : ((1ull << rem) - 1ull));
    }
}

// Column-sliced suppression matrix: Tcol[i*64 + j] bit c = sup(i, c*64+j).
// Diagonal-tile ROW masks: diagR[i] bit j = sup(i, gi*64+j) where gi = i>>6.
__global__ void k_masks(const float* __restrict__ sboxes, unsigned* __restrict__ Tcol,
                        unsigned long long* __restrict__ diagR){
    int i = blockIdx.x;
    int lane = threadIdx.x;
    int gi = i >> 6;
    float cxi = sboxes[i*12+1], cyi = sboxes[i*12+2], wi = sboxes[i*12+3], hi = sboxes[i*12+4];
    float x1i = cxi - wi/2.0f, y1i = cyi - hi/2.0f, x2i = cxi + wi/2.0f, y2i = cyi + hi/2.0f;
    float ari = fmaxf(x2i-x1i, 0.f) * fmaxf(y2i-y1i, 0.f);
    unsigned colbits = 0u;
    for (int c=0; c<24; c++){
        int j = c*64 + lane;
        float cxj = sboxes[j*12+1], cyj = sboxes[j*12+2], wj = sboxes[j*12+3], hj = sboxes[j*12+4];
        float x1j = cxj - wj/2.0f, y1j = cyj - hj/2.0f, x2j = cxj + wj/2.0f, y2j = cyj + hj/2.0f;
        float arj = fmaxf(x2j-x1j, 0.f) * fmaxf(y2j-y1j, 0.f);
        float ix = fmaxf(0.f, fminf(x2i, x2j) - fmaxf(x1i, x1j));
        float iy = fmaxf(0.f, fminf(y2i, y2j) - fmaxf(y1i, y1j));
        float inter = ix * iy;
        float iou = inter / fmaxf(fminf(ari, arj), 1e-9f);
        bool sb = (iou > 0.7f) && (j > i);
        colbits |= sb ? (1u << c) : 0u;
    }
    Tcol[(size_t)i*64 + lane] = colbits;
    unsigned long long rowbits = __ballot(((colbits >> gi) & 1u) != 0u);
    if (lane == 0) diagR[i] = rowbits;
}

__device__ __forceinline__ unsigned long long readlane64(unsigned long long v, int i){
    unsigned lo = (unsigned)__builtin_amdgcn_readlane((int)(unsigned)v, i);
    unsigned hi = (unsigned)__builtin_amdgcn_readlane((int)(unsigned)(v >> 32), i);
    return ((unsigned long long)hi << 32) | (unsigned long long)lo;
}

// Greedy NMS scan:
//  - ALL 4 waves run the resolve redundantly (identical inputs => identical results).
//  - SUPPRESSOR-SKIP resolve: rowR[l] only has bits > l, so
//    Z = ballot(live && (rowR & pend)) is exactly the set of lanes that can
//    change the outcome; the scalar chain visits only Z (typically 0-3 lanes).
//  - Tcol row loads for tile g+1 issued while tile g is merged (latency hidden).
//  - partial[] double-buffered => ONE barrier per tile.
__global__ void k_nms_out(const float* __restrict__ sboxes, const unsigned long long* __restrict__ vwords,
                          const unsigned long long* __restrict__ diagR, const unsigned* __restrict__ Tcol,
                          float* __restrict__ out){
    __shared__ unsigned long long keepw[24];
    __shared__ unsigned partial[2][4][64];
    int t = threadIdx.x;
    int wv = t >> 6, lane = t & 63;
    unsigned SS = 0u;      // bit g = box g*64+lane suppressed; identical in all waves
    unsigned long long rowR = diagR[lane];
    unsigned long long vcur = vwords[0];
    unsigned rows[16];
    {
        const unsigned* b0 = Tcol + (size_t)(wv*16)*64 + lane;
        #pragma unroll
        for (int i=0;i<16;i++) rows[i] = b0[i*64];
    }
    for (int g = 0; g < 24; g++){
        unsigned long long Rnext = (g < 23) ? diagR[(g+1)*64 + lane] : 0ull;
        unsigned long long vnext = (g < 23) ? vwords[g+1] : 0ull;
        bool live = (((vcur >> lane) & 1ull) != 0ull) && (((SS >> g) & 1u) == 0u);
        unsigned long long pend = __ballot(live);
        unsigned long long Z = __ballot(live && ((rowR & pend) != 0ull));
        unsigned long long kept = pend;
        unsigned long long iter = Z;
        while (iter){
            int i = __ffsll((long long)iter) - 1;
            iter &= iter - 1ull;
            if ((kept >> i) & 1ull){
                unsigned long long sup = readlane64(rowR, i);   // only bits > i
                kept &= ~sup;
                iter &= ~sup;
            }
        }
        if (t == 0) keepw[g] = kept;
        unsigned kbits = (unsigned)((kept >> (wv*16)) & 0xFFFFull);   // wave-uniform
        unsigned acc = 0u;
        #pragma unroll
        for (int i=0;i<16;i++) acc |= (0u - ((kbits >> i) & 1u)) & rows[i];
        if (g < 23){
            const unsigned* nb = Tcol + (size_t)((g+1)*64 + wv*16)*64 + lane;
            #pragma unroll
            for (int i=0;i<16;i++) rows[i] = nb[i*64];
        }
        partial[g & 1][wv][lane] = acc;
        __syncthreads();
        SS |= partial[g & 1][0][lane] | partial[g & 1][1][lane]
            | partial[g & 1][2][lane] | partial[g & 1][3][lane];
        rowR = Rnext; vcur = vnext;
    }
    for (int e=t; e<NBOX*9; e+=256){
        int r = e / 9;
        int c = e - r*9;
        bool kp = ((keepw[r >> 6] >> (r & 63)) & 1ull) != 0ull;
        out[e] = kp ? sboxes[r*12 + c] : 0.f;
    }
}

extern "C" void kernel_launch(void* const* d_in, const int* in_sizes, int n_in,
                              void* d_out, int out_size, void* d_ws, size_t ws_size,
                              hipStream_t stream){
    const float* o13 = (const float*)d_in[0];
    const float* o26 = (const float*)d_in[1];
    const float* o52 = (const float*)d_in[2];
    const float* a13 = (const float*)d_in[3];
    const float* a26 = (const float*)d_in[4];
    const float* a52 = (const float*)d_in[5];
    char* ws = (char*)d_ws;
    unsigned* scr             = (unsigned*)(ws);                        // TOTCELL*4 = 1,362,816
    unsigned* Tcol            = (unsigned*)(ws);                        // 393,216 — ALIASES scr (scr dead after k_select)
    int* cnt                  = (int*)(ws + 1362816);                   // 128
    unsigned long long* sel   = (unsigned long long*)(ws + 1362944);    // 12,288
    float* sboxes             = (float*)(ws + 1375232);                 // 73,728
    unsigned long long* vw    = (unsigned long long*)(ws + 1448960);    // 256
    unsigned long long* diagR = (unsigned long long*)(ws + 1449216);    // 12,288 (end ~1.46 MB)
    float* out = (float*)d_out;

    k_score       <<<(TOTCELL + 255)/256, 256, 0, stream>>>(o13, o26, o52, scr);
    k_select      <<<3, 1024, 0, stream>>>(scr, sel, cnt);
    k_decode_merge<<<NBOX/4, 256, 0, stream>>>(o13, o26, o52, a13, a26, a52, sel, cnt, sboxes, vw);
    k_masks       <<<NBOX, 64, 0, stream>>>(sboxes, Tcol, diagR);
    k_nms_out     <<<1, 256, 0, stream>>>(sboxes, vw, diagR, Tcol, out);
}